// Round 10
// baseline (239.116 us; speedup 1.0000x reference)
//
#include <hip/hip_runtime.h>

#define INPUT_SIZE 128
#define OUTPUT_SIZE 128
#define HIDDEN 8
#define BATCH 1024

#define ICH 32                   // i-chunks (blockIdx.y) -> 4096 blocks
#define IPC (INPUT_SIZE / ICH)   // 4 i's per chunk
#define TPB 128                  // threads per block (2 waves)
#define BPT 8                    // batch elements per thread
#define SLOT 60                  // dwords per i-slot: w1h2@0 b1h2@4 b2@8 w3@16 b3@24 W2h@28..59

typedef __fp16 half2v __attribute__((ext_vector_type(2)));

#if defined(__has_builtin)
#if __has_builtin(__builtin_amdgcn_fdot2)
#define HAS_FDOT2 1
#endif
#endif
#ifndef HAS_FDOT2
#define HAS_FDOT2 0
#endif

// ---------------------------------------------------------------------------
// Prep: blocks 0..127 transpose x; 128..1151 W2 fp32->f16; 1152..1279 pack W1
// fp32->half2; 1280..1407 pack b1.
// ---------------------------------------------------------------------------
__global__ void prep_kernel(const float* __restrict__ x,
                            const float* __restrict__ W1,
                            const float* __restrict__ b1,
                            const float* __restrict__ W2,
                            float* __restrict__ xT,
                            unsigned int* __restrict__ W1h,
                            unsigned int* __restrict__ b1h,
                            __fp16* __restrict__ W2h) {
    const int bx = blockIdx.x;
    if (bx < 128) {
        __shared__ float tile[32][33];
        const int i0 = (bx & 3) * 32;
        const int b0 = (bx >> 2) * 32;
        const int tx = threadIdx.x & 31;
        const int ty = threadIdx.x >> 5;
#pragma unroll
        for (int r = ty; r < 32; r += 8)
            tile[r][tx] = x[(b0 + r) * INPUT_SIZE + (i0 + tx)];
        __syncthreads();
#pragma unroll
        for (int r = ty; r < 32; r += 8)
            xT[(i0 + r) * BATCH + (b0 + tx)] = tile[tx][r];
    } else if (bx < 1152) {
        const size_t idx = (size_t)(bx - 128) * 256 + threadIdx.x;
        const float4 v = *(const float4*)(W2 + 4 * idx);
        const half2v a = __builtin_amdgcn_cvt_pkrtz(v.x, v.y);
        const half2v b = __builtin_amdgcn_cvt_pkrtz(v.z, v.w);
        float2 st;
        st.x = __builtin_bit_cast(float, a);
        st.y = __builtin_bit_cast(float, b);
        *(float2*)(W2h + 4 * idx) = st;
    } else if (bx < 1280) {
        const size_t t = (size_t)(bx - 1152) * 256 + threadIdx.x;  // 32768 float4s
        const float4 v = *(const float4*)(W1 + 4 * t);
        W1h[2 * t]     = __builtin_bit_cast(unsigned int, __builtin_amdgcn_cvt_pkrtz(v.x, v.y));
        W1h[2 * t + 1] = __builtin_bit_cast(unsigned int, __builtin_amdgcn_cvt_pkrtz(v.z, v.w));
    } else {
        const size_t t = (size_t)(bx - 1280) * 256 + threadIdx.x;
        const float4 v = *(const float4*)(b1 + 4 * t);
        b1h[2 * t]     = __builtin_bit_cast(unsigned int, __builtin_amdgcn_cvt_pkrtz(v.x, v.y));
        b1h[2 * t + 1] = __builtin_bit_cast(unsigned int, __builtin_amdgcn_cvt_pkrtz(v.z, v.w));
    }
}

__global__ void zero_out_kernel(float* __restrict__ out, int n) {
    int idx = blockIdx.x * blockDim.x + threadIdx.x;
    if (idx < n) out[idx] = 0.0f;
}

// ---------------------------------------------------------------------------
// Main kernel. block=(o,ic). Stage IPC weight slots in LDS once.
// Phase 1: packed-f16 layer 1 (v_pk_fma_f16 + v_pk_max_f16 via native __fp16
// vectors) -> h1p[8][4] half2. Phase 2: fdot2 layer 2 + fp32 layer 3 + acc.
// ---------------------------------------------------------------------------
template <bool PARTIALS>
__global__ __launch_bounds__(TPB, 8)
void mlpkan_kernel(const float* __restrict__ xT,
                   const unsigned int* __restrict__ W1h,
                   const unsigned int* __restrict__ b1h,
                   const __fp16* __restrict__ W2h, const float* __restrict__ b2,
                   const float* __restrict__ W3, const float* __restrict__ b3,
                   float* __restrict__ partials, float* __restrict__ out) {
    __shared__ float wlds[IPC * SLOT];

    const int o   = blockIdx.x;
    const int ic  = blockIdx.y;
    const int tid = threadIdx.x;

    // ---- stage weights: 16 threads per i-slot (slots 0..IPC-1) ----
    {
        const int ii  = tid >> 4;
        const int idx = tid & 15;
        if (ii < IPC) {
            const int n = (ic * IPC + ii) * OUTPUT_SIZE + o;
            float* d = &wlds[ii * SLOT];
            if (idx == 0)      *(float4*)(d + 0)  = *(const float4*)((const float*)W1h + (size_t)n * 4);
            else if (idx == 1) *(float4*)(d + 4)  = *(const float4*)((const float*)b1h + (size_t)n * 4);
            else if (idx == 2) *(float4*)(d + 8)  = *(const float4*)(b2 + (size_t)n * 8);
            else if (idx == 3) *(float4*)(d + 12) = *(const float4*)(b2 + (size_t)n * 8 + 4);
            else if (idx == 4) *(float4*)(d + 16) = *(const float4*)(W3 + (size_t)n * 8);
            else if (idx == 5) *(float4*)(d + 20) = *(const float4*)(W3 + (size_t)n * 8 + 4);
            else if (idx == 6) d[24] = b3[n];
            else if (idx >= 8) *(float4*)(d + 28 + 4 * (idx - 8)) =
                *(const float4*)((const char*)W2h + (size_t)n * 128 + (idx - 8) * 16);
        }
    }
    __syncthreads();

    float acc[BPT];
#pragma unroll
    for (int j = 0; j < BPT; ++j) acc[j] = 0.0f;

#pragma unroll 1
    for (int ii = 0; ii < IPC; ++ii) {
        const int i = ic * IPC + ii;
        const float* w = &wlds[ii * SLOT];

        const float4 sA = *(const float4*)(xT + (size_t)i * BATCH + 4 * tid);
        const float4 sB = *(const float4*)(xT + (size_t)i * BATCH + 512 + 4 * tid);
        const float s[BPT] = {sA.x, sA.y, sA.z, sA.w, sB.x, sB.y, sB.z, sB.w};

        // ---------------- phase 1: packed-f16 layer 1 ----------------
        const float4 w1q = *(const float4*)(w + 0);
        const float4 b1q = *(const float4*)(w + 4);
        const half2v w1p[4] = {__builtin_bit_cast(half2v, w1q.x), __builtin_bit_cast(half2v, w1q.y),
                               __builtin_bit_cast(half2v, w1q.z), __builtin_bit_cast(half2v, w1q.w)};
        const half2v b1p[4] = {__builtin_bit_cast(half2v, b1q.x), __builtin_bit_cast(half2v, b1q.y),
                               __builtin_bit_cast(half2v, b1q.z), __builtin_bit_cast(half2v, b1q.w)};
        const half2v zero2 = {(__fp16)0.0f, (__fp16)0.0f};

        half2v h1p[BPT][4];
#pragma unroll
        for (int j = 0; j < BPT; ++j) {
            const half2v xx = __builtin_amdgcn_cvt_pkrtz(s[j], s[j]);
#pragma unroll
            for (int q = 0; q < 4; ++q) {
                const half2v v = w1p[q] * xx + b1p[q];          // v_pk_fma_f16
                h1p[j][q] = __builtin_elementwise_max(v, zero2); // v_pk_max_f16
            }
        }

        // ---------------- phase 2: fdot2 layer 2 + fp32 layer 3 ----------------
        const float4 b2a = *(const float4*)(w + 8);
        const float4 b2b = *(const float4*)(w + 12);
        const float4 w3a = *(const float4*)(w + 16);
        const float4 w3b = *(const float4*)(w + 20);
        const float  b3r = w[24];
        const float b2r[8] = {b2a.x, b2a.y, b2a.z, b2a.w, b2b.x, b2b.y, b2b.z, b2b.w};
        const float w3r[8] = {w3a.x, w3a.y, w3a.z, w3a.w, w3b.x, w3b.y, w3b.z, w3b.w};

        half2v w2p[8][4];
#pragma unroll
        for (int r = 0; r < 8; ++r) {
            const float4 row = *(const float4*)(w + 28 + 4 * r);
            w2p[r][0] = __builtin_bit_cast(half2v, row.x);
            w2p[r][1] = __builtin_bit_cast(half2v, row.y);
            w2p[r][2] = __builtin_bit_cast(half2v, row.z);
            w2p[r][3] = __builtin_bit_cast(half2v, row.w);
        }

#pragma unroll
        for (int j = 0; j < BPT; ++j) {
            float h2[8];
#if HAS_FDOT2
#pragma unroll
            for (int h = 0; h < 8; ++h) {
                float v = b2r[h];
#pragma unroll
                for (int q = 0; q < 4; ++q)
                    v = __builtin_amdgcn_fdot2(w2p[h][q], h1p[j][q], v, false);
                h2[h] = fmaxf(v, 0.0f);
            }
#else
#pragma unroll
            for (int h = 0; h < 8; ++h) {
                float v = b2r[h];
#pragma unroll
                for (int q = 0; q < 4; ++q) {
                    v = fmaf((float)w2p[h][q][0], (float)h1p[j][q][0], v);
                    v = fmaf((float)w2p[h][q][1], (float)h1p[j][q][1], v);
                }
                h2[h] = fmaxf(v, 0.0f);
            }
#endif
            float v3 = b3r;
#pragma unroll
            for (int k = 0; k < 8; ++k)
                v3 = fmaf(w3r[k], h2[k], v3);
            acc[j] += v3;
        }
    }

    if (PARTIALS) {
        float* base = partials + ((size_t)ic * OUTPUT_SIZE + o) * BATCH;
        float4 pa = {acc[0], acc[1], acc[2], acc[3]};
        float4 pb = {acc[4], acc[5], acc[6], acc[7]};
        *(float4*)(base + 4 * tid)       = pa;
        *(float4*)(base + 512 + 4 * tid) = pb;
    } else {
#pragma unroll
        for (int j = 0; j < BPT; ++j) {
            const int b = (j < 4) ? (4 * tid + j) : (512 + 4 * tid + (j - 4));
            atomicAdd(&out[(size_t)b * OUTPUT_SIZE + o], acc[j]);
        }
    }
}

// ---------------------------------------------------------------------------
// Reduce ICH partials [ic][o][b] -> out [b][o] with LDS transpose.
// ---------------------------------------------------------------------------
__global__ void reduce_kernel(const float* __restrict__ partials,
                              float* __restrict__ out) {
    __shared__ float tile[32][33];
    const int o0 = blockIdx.x * 32;
    const int b0 = blockIdx.y * 32;
    const int tx = threadIdx.x;
    const int ty = threadIdx.y;
#pragma unroll
    for (int r = ty; r < 32; r += 16) {
        float v = 0.0f;
#pragma unroll
        for (int icc = 0; icc < ICH; ++icc)
            v += partials[((size_t)icc * OUTPUT_SIZE + o0 + r) * BATCH + b0 + tx];
        tile[r][tx] = v;
    }
    __syncthreads();
#pragma unroll
    for (int r = ty; r < 32; r += 16)
        out[(size_t)(b0 + r) * OUTPUT_SIZE + o0 + tx] = tile[tx][r];
}

extern "C" void kernel_launch(void* const* d_in, const int* in_sizes, int n_in,
                              void* d_out, int out_size, void* d_ws, size_t ws_size,
                              hipStream_t stream) {
    const float* x  = (const float*)d_in[0];
    const float* W1 = (const float*)d_in[1];
    const float* b1 = (const float*)d_in[2];
    const float* W2 = (const float*)d_in[3];
    const float* b2 = (const float*)d_in[4];
    const float* W3 = (const float*)d_in[5];
    const float* b3 = (const float*)d_in[6];
    float* out = (float*)d_out;

    const size_t xt_elems   = (size_t)INPUT_SIZE * BATCH;               // 128K f
    const size_t part_elems = (size_t)ICH * OUTPUT_SIZE * BATCH;        // 4M f
    const size_t w2h_bytes  = (size_t)16384 * 64 * sizeof(__fp16);      // 2MB
    const size_t w1h_elems  = (size_t)16384 * 4;                        // 64K uints
    const size_t need_bytes = (xt_elems + part_elems) * sizeof(float) + w2h_bytes
                            + 2 * w1h_elems * sizeof(unsigned int);

    dim3 mgrid(OUTPUT_SIZE, ICH);

    if (ws_size >= need_bytes) {
        float*        xT       = (float*)d_ws;
        float*        partials = xT + xt_elems;
        __fp16*       W2h      = (__fp16*)(partials + part_elems);
        unsigned int* W1h      = (unsigned int*)((char*)W2h + w2h_bytes);
        unsigned int* b1h      = W1h + w1h_elems;

        prep_kernel<<<1408, 256, 0, stream>>>(x, W1, b1, W2, xT, W1h, b1h, W2h);
        mlpkan_kernel<true><<<mgrid, TPB, 0, stream>>>(xT, W1h, b1h, W2h, b2, W3, b3,
                                                       partials, out);
        dim3 rgrid(OUTPUT_SIZE / 32, BATCH / 32);
        reduce_kernel<<<rgrid, dim3(32, 16), 0, stream>>>(partials, out);
    } else {
        const int nz = BATCH * OUTPUT_SIZE;
        zero_out_kernel<<<(nz + 255) / 256, 256, 0, stream>>>(out, nz);
        if (ws_size >= xt_elems * sizeof(float) + w2h_bytes + 2 * w1h_elems * sizeof(unsigned int)) {
            float*        xT  = (float*)d_ws;
            __fp16*       W2h = (__fp16*)(xT + xt_elems);
            unsigned int* W1h = (unsigned int*)((char*)W2h + w2h_bytes);
            unsigned int* b1h = W1h + w1h_elems;
            prep_kernel<<<1408, 256, 0, stream>>>(x, W1, b1, W2, xT, W1h, b1h, W2h);
            mlpkan_kernel<false><<<mgrid, TPB, 0, stream>>>(xT, W1h, b1h, W2h, b2, W3, b3,
                                                            nullptr, out);
        }
    }
}

// Round 11
// 108.412 us; speedup vs baseline: 2.2056x; 2.2056x over previous
//
#include <hip/hip_runtime.h>

#define INPUT_SIZE 128
#define OUTPUT_SIZE 128
#define HIDDEN 8
#define BATCH 1024

#define ICH 32                   // i-chunks (blockIdx.y) -> 4096 blocks
#define IPC (INPUT_SIZE / ICH)   // 4 i's per chunk
#define TPB 128                  // threads per block (2 waves)
#define BPT 8                    // batch elements per thread
#define SLOT 60                  // dwords per i-slot: w1h2@0 b1h2@4 b2@8 w3@16 b3@24 W2h@28..59

typedef __fp16 half2v __attribute__((ext_vector_type(2)));

#if defined(__has_builtin)
#if __has_builtin(__builtin_amdgcn_fdot2)
#define HAS_FDOT2 1
#endif
#endif
#ifndef HAS_FDOT2
#define HAS_FDOT2 0
#endif

// ---------------------------------------------------------------------------
// Prep: blocks 0..127 transpose x; 128..1151 W2 fp32->f16; 1152..1279 pack W1
// fp32->half2; 1280..1407 pack b1.
// ---------------------------------------------------------------------------
__global__ void prep_kernel(const float* __restrict__ x,
                            const float* __restrict__ W1,
                            const float* __restrict__ b1,
                            const float* __restrict__ W2,
                            float* __restrict__ xT,
                            unsigned int* __restrict__ W1h,
                            unsigned int* __restrict__ b1h,
                            __fp16* __restrict__ W2h) {
    const int bx = blockIdx.x;
    if (bx < 128) {
        __shared__ float tile[32][33];
        const int i0 = (bx & 3) * 32;
        const int b0 = (bx >> 2) * 32;
        const int tx = threadIdx.x & 31;
        const int ty = threadIdx.x >> 5;
#pragma unroll
        for (int r = ty; r < 32; r += 8)
            tile[r][tx] = x[(b0 + r) * INPUT_SIZE + (i0 + tx)];
        __syncthreads();
#pragma unroll
        for (int r = ty; r < 32; r += 8)
            xT[(i0 + r) * BATCH + (b0 + tx)] = tile[tx][r];
    } else if (bx < 1152) {
        const size_t idx = (size_t)(bx - 128) * 256 + threadIdx.x;
        const float4 v = *(const float4*)(W2 + 4 * idx);
        const half2v a = __builtin_amdgcn_cvt_pkrtz(v.x, v.y);
        const half2v b = __builtin_amdgcn_cvt_pkrtz(v.z, v.w);
        float2 st;
        st.x = __builtin_bit_cast(float, a);
        st.y = __builtin_bit_cast(float, b);
        *(float2*)(W2h + 4 * idx) = st;
    } else if (bx < 1280) {
        const size_t t = (size_t)(bx - 1152) * 256 + threadIdx.x;  // 32768 float4s
        const float4 v = *(const float4*)(W1 + 4 * t);
        W1h[2 * t]     = __builtin_bit_cast(unsigned int, __builtin_amdgcn_cvt_pkrtz(v.x, v.y));
        W1h[2 * t + 1] = __builtin_bit_cast(unsigned int, __builtin_amdgcn_cvt_pkrtz(v.z, v.w));
    } else {
        const size_t t = (size_t)(bx - 1280) * 256 + threadIdx.x;
        const float4 v = *(const float4*)(b1 + 4 * t);
        b1h[2 * t]     = __builtin_bit_cast(unsigned int, __builtin_amdgcn_cvt_pkrtz(v.x, v.y));
        b1h[2 * t + 1] = __builtin_bit_cast(unsigned int, __builtin_amdgcn_cvt_pkrtz(v.z, v.w));
    }
}

__global__ void zero_out_kernel(float* __restrict__ out, int n) {
    int idx = blockIdx.x * blockDim.x + threadIdx.x;
    if (idx < n) out[idx] = 0.0f;
}

// ---------------------------------------------------------------------------
// Main kernel. block=(o,ic). Stage IPC weight slots in LDS once.
// Phase 1: packed-f16 layer 1 -> h1p[8][4] half2.
// Phase 2: fdot2 layer 2 + fp32 layer 3 + acc.
// launch_bounds(128,4): VGPR cap 128 — rnd10's (,8) cap=~32 caused full spill
// (FETCH 288MB / WRITE 482MB scratch traffic). Keep cap >= live set (~90).
// ---------------------------------------------------------------------------
template <bool PARTIALS>
__global__ __launch_bounds__(TPB, 4)
void mlpkan_kernel(const float* __restrict__ xT,
                   const unsigned int* __restrict__ W1h,
                   const unsigned int* __restrict__ b1h,
                   const __fp16* __restrict__ W2h, const float* __restrict__ b2,
                   const float* __restrict__ W3, const float* __restrict__ b3,
                   float* __restrict__ partials, float* __restrict__ out) {
    __shared__ float wlds[IPC * SLOT];

    const int o   = blockIdx.x;
    const int ic  = blockIdx.y;
    const int tid = threadIdx.x;

    // ---- stage weights: 16 threads per i-slot (slots 0..IPC-1) ----
    {
        const int ii  = tid >> 4;
        const int idx = tid & 15;
        if (ii < IPC) {
            const int n = (ic * IPC + ii) * OUTPUT_SIZE + o;
            float* d = &wlds[ii * SLOT];
            if (idx == 0)      *(float4*)(d + 0)  = *(const float4*)((const float*)W1h + (size_t)n * 4);
            else if (idx == 1) *(float4*)(d + 4)  = *(const float4*)((const float*)b1h + (size_t)n * 4);
            else if (idx == 2) *(float4*)(d + 8)  = *(const float4*)(b2 + (size_t)n * 8);
            else if (idx == 3) *(float4*)(d + 12) = *(const float4*)(b2 + (size_t)n * 8 + 4);
            else if (idx == 4) *(float4*)(d + 16) = *(const float4*)(W3 + (size_t)n * 8);
            else if (idx == 5) *(float4*)(d + 20) = *(const float4*)(W3 + (size_t)n * 8 + 4);
            else if (idx == 6) d[24] = b3[n];
            else if (idx >= 8) *(float4*)(d + 28 + 4 * (idx - 8)) =
                *(const float4*)((const char*)W2h + (size_t)n * 128 + (idx - 8) * 16);
        }
    }
    __syncthreads();

    float acc[BPT];
#pragma unroll
    for (int j = 0; j < BPT; ++j) acc[j] = 0.0f;

#pragma unroll 1
    for (int ii = 0; ii < IPC; ++ii) {
        const int i = ic * IPC + ii;
        const float* w = &wlds[ii * SLOT];

        const float4 sA = *(const float4*)(xT + (size_t)i * BATCH + 4 * tid);
        const float4 sB = *(const float4*)(xT + (size_t)i * BATCH + 512 + 4 * tid);
        const float s[BPT] = {sA.x, sA.y, sA.z, sA.w, sB.x, sB.y, sB.z, sB.w};

        // ---------------- phase 1: packed-f16 layer 1 ----------------
        const float4 w1q = *(const float4*)(w + 0);
        const float4 b1q = *(const float4*)(w + 4);
        const half2v w1p[4] = {__builtin_bit_cast(half2v, w1q.x), __builtin_bit_cast(half2v, w1q.y),
                               __builtin_bit_cast(half2v, w1q.z), __builtin_bit_cast(half2v, w1q.w)};
        const half2v b1p[4] = {__builtin_bit_cast(half2v, b1q.x), __builtin_bit_cast(half2v, b1q.y),
                               __builtin_bit_cast(half2v, b1q.z), __builtin_bit_cast(half2v, b1q.w)};
        const half2v zero2 = {(__fp16)0.0f, (__fp16)0.0f};

        half2v h1p[BPT][4];
#pragma unroll
        for (int j = 0; j < BPT; ++j) {
            const half2v xx = __builtin_amdgcn_cvt_pkrtz(s[j], s[j]);
#pragma unroll
            for (int q = 0; q < 4; ++q) {
                const half2v v = w1p[q] * xx + b1p[q];           // v_pk_fma_f16
                h1p[j][q] = __builtin_elementwise_max(v, zero2); // v_pk_max_f16
            }
        }

        // ---------------- phase 2: fdot2 layer 2 + fp32 layer 3 ----------------
        const float4 b2a = *(const float4*)(w + 8);
        const float4 b2b = *(const float4*)(w + 12);
        const float4 w3a = *(const float4*)(w + 16);
        const float4 w3b = *(const float4*)(w + 20);
        const float  b3r = w[24];
        const float b2r[8] = {b2a.x, b2a.y, b2a.z, b2a.w, b2b.x, b2b.y, b2b.z, b2b.w};
        const float w3r[8] = {w3a.x, w3a.y, w3a.z, w3a.w, w3b.x, w3b.y, w3b.z, w3b.w};

        half2v w2p[8][4];
#pragma unroll
        for (int r = 0; r < 8; ++r) {
            const float4 row = *(const float4*)(w + 28 + 4 * r);
            w2p[r][0] = __builtin_bit_cast(half2v, row.x);
            w2p[r][1] = __builtin_bit_cast(half2v, row.y);
            w2p[r][2] = __builtin_bit_cast(half2v, row.z);
            w2p[r][3] = __builtin_bit_cast(half2v, row.w);
        }

#pragma unroll
        for (int j = 0; j < BPT; ++j) {
            float h2[8];
#if HAS_FDOT2
#pragma unroll
            for (int h = 0; h < 8; ++h) {
                float v = b2r[h];
#pragma unroll
                for (int q = 0; q < 4; ++q)
                    v = __builtin_amdgcn_fdot2(w2p[h][q], h1p[j][q], v, false);
                h2[h] = fmaxf(v, 0.0f);
            }
#else
#pragma unroll
            for (int h = 0; h < 8; ++h) {
                float v = b2r[h];
#pragma unroll
                for (int q = 0; q < 4; ++q) {
                    v = fmaf((float)w2p[h][q][0], (float)h1p[j][q][0], v);
                    v = fmaf((float)w2p[h][q][1], (float)h1p[j][q][1], v);
                }
                h2[h] = fmaxf(v, 0.0f);
            }
#endif
            float v3 = b3r;
#pragma unroll
            for (int k = 0; k < 8; ++k)
                v3 = fmaf(w3r[k], h2[k], v3);
            acc[j] += v3;
        }
    }

    if (PARTIALS) {
        float* base = partials + ((size_t)ic * OUTPUT_SIZE + o) * BATCH;
        float4 pa = {acc[0], acc[1], acc[2], acc[3]};
        float4 pb = {acc[4], acc[5], acc[6], acc[7]};
        *(float4*)(base + 4 * tid)       = pa;
        *(float4*)(base + 512 + 4 * tid) = pb;
    } else {
#pragma unroll
        for (int j = 0; j < BPT; ++j) {
            const int b = (j < 4) ? (4 * tid + j) : (512 + 4 * tid + (j - 4));
            atomicAdd(&out[(size_t)b * OUTPUT_SIZE + o], acc[j]);
        }
    }
}

// ---------------------------------------------------------------------------
// Reduce ICH partials [ic][o][b] -> out [b][o] with LDS transpose.
// ---------------------------------------------------------------------------
__global__ void reduce_kernel(const float* __restrict__ partials,
                              float* __restrict__ out) {
    __shared__ float tile[32][33];
    const int o0 = blockIdx.x * 32;
    const int b0 = blockIdx.y * 32;
    const int tx = threadIdx.x;
    const int ty = threadIdx.y;
#pragma unroll
    for (int r = ty; r < 32; r += 16) {
        float v = 0.0f;
#pragma unroll
        for (int icc = 0; icc < ICH; ++icc)
            v += partials[((size_t)icc * OUTPUT_SIZE + o0 + r) * BATCH + b0 + tx];
        tile[r][tx] = v;
    }
    __syncthreads();
#pragma unroll
    for (int r = ty; r < 32; r += 16)
        out[(size_t)(b0 + r) * OUTPUT_SIZE + o0 + tx] = tile[tx][r];
}

extern "C" void kernel_launch(void* const* d_in, const int* in_sizes, int n_in,
                              void* d_out, int out_size, void* d_ws, size_t ws_size,
                              hipStream_t stream) {
    const float* x  = (const float*)d_in[0];
    const float* W1 = (const float*)d_in[1];
    const float* b1 = (const float*)d_in[2];
    const float* W2 = (const float*)d_in[3];
    const float* b2 = (const float*)d_in[4];
    const float* W3 = (const float*)d_in[5];
    const float* b3 = (const float*)d_in[6];
    float* out = (float*)d_out;

    const size_t xt_elems   = (size_t)INPUT_SIZE * BATCH;               // 128K f
    const size_t part_elems = (size_t)ICH * OUTPUT_SIZE * BATCH;        // 4M f
    const size_t w2h_bytes  = (size_t)16384 * 64 * sizeof(__fp16);      // 2MB
    const size_t w1h_elems  = (size_t)16384 * 4;                        // 64K uints
    const size_t need_bytes = (xt_elems + part_elems) * sizeof(float) + w2h_bytes
                            + 2 * w1h_elems * sizeof(unsigned int);

    dim3 mgrid(OUTPUT_SIZE, ICH);

    if (ws_size >= need_bytes) {
        float*        xT       = (float*)d_ws;
        float*        partials = xT + xt_elems;
        __fp16*       W2h      = (__fp16*)(partials + part_elems);
        unsigned int* W1h      = (unsigned int*)((char*)W2h + w2h_bytes);
        unsigned int* b1h      = W1h + w1h_elems;

        prep_kernel<<<1408, 256, 0, stream>>>(x, W1, b1, W2, xT, W1h, b1h, W2h);
        mlpkan_kernel<true><<<mgrid, TPB, 0, stream>>>(xT, W1h, b1h, W2h, b2, W3, b3,
                                                       partials, out);
        dim3 rgrid(OUTPUT_SIZE / 32, BATCH / 32);
        reduce_kernel<<<rgrid, dim3(32, 16), 0, stream>>>(partials, out);
    } else {
        const int nz = BATCH * OUTPUT_SIZE;
        zero_out_kernel<<<(nz + 255) / 256, 256, 0, stream>>>(out, nz);
        if (ws_size >= xt_elems * sizeof(float) + w2h_bytes + 2 * w1h_elems * sizeof(unsigned int)) {
            float*        xT  = (float*)d_ws;
            __fp16*       W2h = (__fp16*)(xT + xt_elems);
            unsigned int* W1h = (unsigned int*)((char*)W2h + w2h_bytes);
            unsigned int* b1h = W1h + w1h_elems;
            prep_kernel<<<1408, 256, 0, stream>>>(x, W1, b1, W2, xT, W1h, b1h, W2h);
            mlpkan_kernel<false><<<mgrid, TPB, 0, stream>>>(xT, W1h, b1h, W2h, b2, W3, b3,
                                                            nullptr, out);
        }
    }
}